// Round 10
// baseline (385.217 us; speedup 1.0000x reference)
//
#include <hip/hip_runtime.h>
#include <hip/hip_cooperative_groups.h>
#include <math.h>

namespace cg = cooperative_groups;

#define IN_SIZE 128
#define E_SIZE  32
#define KDIM    160
#define BSHIFT  6                    // 64 nodes per bucket
#define BNODES  (1 << BSHIFT)
#define NBK_MAX 1024                 // nbk = ceil(50000/64) = 782 <= 1024
#define NSCAT   256                  // blocks doing hist/scatter phases

typedef __attribute__((ext_vector_type(8))) short short8v;
typedef __attribute__((ext_vector_type(4))) float f32x4;

// ---------------- fused CSR build: hist -> scan -> scatter -> per-bucket fill ----------------
// cooperative launch, grid = nbk blocks x 256 threads, grid.sync() between phases.

__global__ __launch_bounds__(256) void k_csr(
    const int* __restrict__ dst, int* __restrict__ slabA, int* __restrict__ slabB,
    int* __restrict__ bktcnt, int* __restrict__ bktbase, int* __restrict__ bin,
    int* __restrict__ eids, int* __restrict__ offsets, int E, int N, int nbk)
{
    cg::grid_group grid = cg::this_grid();
    __shared__ int shA[NBK_MAX];
    __shared__ int shB[NBK_MAX];
    __shared__ int shW[4];
    __shared__ int shCnt[BNODES];
    __shared__ int shNb0[BNODES];
    int b = blockIdx.x, tid = threadIdx.x;
    int lane = tid & 63, wv = tid >> 6;

    // ---- P1: per-block bucket histogram -> slabA ----
    if (b < NSCAT) {
        for (int k = tid; k < nbk; k += 256) shA[k] = 0;
        __syncthreads();
        int chunk = (E + NSCAT - 1) / NSCAT;
        int s = b * chunk;
        int e = s + chunk; if (e > E) e = E;
        for (int i = s + tid; i < e; i += 256)
            atomicAdd(&shA[dst[i] >> BSHIFT], 1);
        __syncthreads();
        for (int k = tid; k < nbk; k += 256)
            slabA[b * nbk + k] = shA[k];
    }
    grid.sync();

    // ---- P2: per-bucket prefix over the NSCAT block counts (bucket b) ----
    if (b < nbk) {
        int v = slabA[tid * nbk + b];
        int x = v;
        #pragma unroll
        for (int off = 1; off < 64; off <<= 1) {
            int y = __shfl_up(x, off);
            if (lane >= off) x += y;
        }
        if (lane == 63) shW[wv] = x;
        __syncthreads();
        if (tid == 0) {
            int r = 0;
            #pragma unroll
            for (int w = 0; w < 4; ++w) { int t2 = shW[w]; shW[w] = r; r += t2; }
        }
        __syncthreads();
        int incl = shW[wv] + x;
        slabB[tid * nbk + b] = incl - v;             // exclusive within-bucket base for block tid
        if (tid == 255) bktcnt[b] = incl;
    }
    grid.sync();

    // ---- P3: scatter (single dst pass, LDS cursors; block 0 publishes bktbase) ----
    if (b < NSCAT) {
        // in-LDS exclusive scan of bktcnt (4 per thread) -> shA = bucket bases
        {
            int k0 = tid * 4;
            int v0 = (k0 + 0 < nbk) ? bktcnt[k0 + 0] : 0;
            int v1 = (k0 + 1 < nbk) ? bktcnt[k0 + 1] : 0;
            int v2 = (k0 + 2 < nbk) ? bktcnt[k0 + 2] : 0;
            int v3 = (k0 + 3 < nbk) ? bktcnt[k0 + 3] : 0;
            int tsum = v0 + v1 + v2 + v3;
            int x = tsum;
            #pragma unroll
            for (int off = 1; off < 64; off <<= 1) {
                int y = __shfl_up(x, off);
                if (lane >= off) x += y;
            }
            if (lane == 63) shW[wv] = x;
            __syncthreads();
            if (tid == 0) {
                int r = 0;
                #pragma unroll
                for (int w = 0; w < 4; ++w) { int t2 = shW[w]; shW[w] = r; r += t2; }
            }
            __syncthreads();
            int ex = shW[wv] + (x - tsum);
            shA[k0 + 0] = ex;
            shA[k0 + 1] = ex + v0;
            shA[k0 + 2] = ex + v0 + v1;
            shA[k0 + 3] = ex + v0 + v1 + v2;
            __syncthreads();
        }
        for (int k = tid; k < nbk; k += 256)
            shB[k] = shA[k] + slabB[b * nbk + k];    // global cursor for this block
        if (b == 0) {
            for (int k = tid; k < nbk; k += 256) bktbase[k] = shA[k];
            if (tid == 0) { bktbase[nbk] = E; offsets[N] = E; }
        }
        __syncthreads();
        int chunk = (E + NSCAT - 1) / NSCAT;
        int s = b * chunk;
        int e = s + chunk; if (e > E) e = E;
        for (int i = s + tid; i < e; i += 256) {
            int d = dst[i];
            int p = atomicAdd(&shB[d >> BSHIFT], 1);
            bin[p] = (i << BSHIFT) | (d & (BNODES - 1));
        }
    }
    grid.sync();

    // ---- P4: per-bucket exact placement + offsets (bucket b) ----
    if (b < nbk) {
        int n0 = b << BSHIFT;
        int s = bktbase[b];
        int e = bktbase[b + 1];
        if (tid < BNODES) shCnt[tid] = 0;
        __syncthreads();
        for (int k = s + tid; k < e; k += 256)
            atomicAdd(&shCnt[bin[k] & (BNODES - 1)], 1);
        __syncthreads();
        if (tid < BNODES) {                          // wave 0: shuffle scan of 64 degrees
            int v = shCnt[tid], x = v;
            #pragma unroll
            for (int off = 1; off < 64; off <<= 1) {
                int y = __shfl_up(x, off);
                if (tid >= off) x += y;
            }
            int nodebase = s + x - v;
            shNb0[tid] = nodebase;
            if (n0 + tid < N) offsets[n0 + tid] = nodebase;
            shCnt[tid] = 0;                          // reuse as cursor
        }
        __syncthreads();
        for (int k = s + tid; k < e; k += 256) {
            int pk = bin[k];
            int ln = pk & (BNODES - 1);
            int p = shNb0[ln] + atomicAdd(&shCnt[ln], 1);
            eids[p] = pk >> BSHIFT;
        }
    }
}

// ---------------- per-node aggregate (1 wave / node, 8 edges x 8 float4-lanes) ----------------

__device__ __forceinline__ float red_q(float x) {        // sum across q (lane bits 0..2)
    x += __shfl_xor(x, 1); x += __shfl_xor(x, 2); x += __shfl_xor(x, 4);
    return x;
}
__device__ __forceinline__ float red_es(float x) {       // sum across es (lane bits 3..5)
    x += __shfl_xor(x, 8); x += __shfl_xor(x, 16); x += __shfl_xor(x, 32);
    return x;
}
__device__ __forceinline__ float4 red_es4(float4 v) {
    v.x = red_es(v.x); v.y = red_es(v.y); v.z = red_es(v.z); v.w = red_es(v.w);
    return v;
}

template<int NIT>
__device__ __forceinline__ float4 node_aggregate(
    const float* __restrict__ ef, const int* __restrict__ eids,
    int start, int deg, int lane, int es, int q)
{
    int myeid = (lane < deg) ? eids[start + lane] : 0;

    float4 fc[NIT];
    #pragma unroll
    for (int it = 0; it < NIT; ++it) {
        int i = es + it * 8;
        int eid = __shfl(myeid, i);
        float4 f = make_float4(0.f, 0.f, 0.f, 0.f);
        if (i < deg)
            f = *(const float4*)&ef[(size_t)eid * E_SIZE + q * 4];
        fc[it] = f;
    }

    float4 esum = make_float4(0.f, 0.f, 0.f, 0.f);
    #pragma unroll
    for (int it = 0; it < NIT; ++it) {
        esum.x += fc[it].x; esum.y += fc[it].y; esum.z += fc[it].z; esum.w += fc[it].w;
    }
    for (int i = es + NIT * 8; i < deg; i += 8) {       // overflow: ~never
        int eid = eids[start + i];
        float4 f = *(const float4*)&ef[(size_t)eid * E_SIZE + q * 4];
        esum.x += f.x; esum.y += f.y; esum.z += f.z; esum.w += f.w;
    }
    esum = red_es4(esum);
    float inv = (deg > 0) ? 1.f / (float)deg : 0.f;
    float4 hk = make_float4(esum.x * inv, esum.y * inv, esum.z * inv, esum.w * inv);
    float hn2 = hk.x * hk.x + hk.y * hk.y + hk.z * hk.z + hk.w * hk.w;
    hn2 = red_q(hn2);
    float t2h = 0.25f * hn2;

    float4 ssum = make_float4(0.f, 0.f, 0.f, 0.f);
    float scnt = 0.f;
    #pragma unroll
    for (int it = 0; it < NIT; ++it) {
        float4 f = fc[it];
        float num = hk.x * f.x + hk.y * f.y + hk.z * f.z + hk.w * f.w;
        float fn2 = f.x * f.x + f.y * f.y + f.z * f.z + f.w * f.w;
        num = red_q(num);
        fn2 = red_q(fn2);
        if (num < 0.f || num * num < t2h * fn2) {
            ssum.x += f.x; ssum.y += f.y; ssum.z += f.z; ssum.w += f.w;
            scnt += (es + it * 8 < deg) ? 1.f : 0.f;
        }
    }
    for (int i = es + NIT * 8; i < deg; i += 8) {       // overflow: ~never
        int eid = eids[start + i];
        float4 f = *(const float4*)&ef[(size_t)eid * E_SIZE + q * 4];
        float num = hk.x * f.x + hk.y * f.y + hk.z * f.z + hk.w * f.w;
        float fn2 = f.x * f.x + f.y * f.y + f.z * f.z + f.w * f.w;
        num = red_q(num);
        fn2 = red_q(fn2);
        if (num < 0.f || num * num < t2h * fn2) {
            ssum.x += f.x; ssum.y += f.y; ssum.z += f.z; ssum.w += f.w;
            scnt += 1.f;
        }
    }
    ssum = red_es4(ssum);
    scnt = red_es(scnt);

    float4 a;
    if (scnt > 0.f) {
        float r = 1.f / scnt;
        a = make_float4(ssum.x * r, ssum.y * r, ssum.z * r, ssum.w * r);
    } else {
        a = hk;
    }
    return a;
}

__global__ __launch_bounds__(256, 6) void k_node(
    const float* __restrict__ ef, const int* __restrict__ offsets,
    const int* __restrict__ eids, float* __restrict__ agg, int N)
{
    int wid = blockIdx.x * 4 + (threadIdx.x >> 6);   // node id
    if (wid >= N) return;
    int lane = threadIdx.x & 63;
    int es = lane >> 3;
    int q  = lane & 7;
    int start = offsets[wid];
    int deg   = offsets[wid + 1] - start;

    float4 a;
    if (deg <= 32) a = node_aggregate<4>(ef, eids, start, deg, lane, es, q);
    else           a = node_aggregate<8>(ef, eids, start, deg, lane, es, q);

    if (es == 0) *(float4*)&agg[(size_t)wid * E_SIZE + q * 4] = a;
}

// ---------------- GEMM (bf16 MFMA): out[N][128] = [h_in | agg] @ W^T ----------------
// BM=64, BN=128 (full), K=160=5x32; 782 blocks, 256 thr = 4 waves; wave w owns rows w*16..+15.
// mfma_f32_16x16x32_bf16 lane maps: a: row=lane&15, k=(lane>>4)*8+i; b: col=lane&15, same k;
// d: row=(lane>>4)*4+j, col=lane&15. f32 accumulate keeps bf16 rounding error ~1e-2 << threshold.

__device__ __forceinline__ unsigned short f2bf(float x) {   // RNE fp32->bf16
    union { float f; unsigned int u; } c; c.f = x;
    unsigned int r = c.u + 0x7FFFu + ((c.u >> 16) & 1u);
    return (unsigned short)(r >> 16);
}

__global__ __launch_bounds__(256) void k_gemm(
    const float* __restrict__ A0,   // h_in [N][128]
    const float* __restrict__ A1,   // agg  [N][32]
    const float* __restrict__ W,    // [128][160]
    float* __restrict__ out, int N)
{
    __shared__ unsigned short As[64][40];    // bf16, pad-40: 16B-aligned rows, <=2-way banks
    __shared__ unsigned short Bs[128][40];   // Bs[n][kk] = W[n][k0+kk] (bf16)
    int t = threadIdx.x;
    int m0 = blockIdx.x * 64;
    int w = t >> 6, lane = t & 63;
    int lr = lane & 15;          // row (A) / col (B,D) within 16
    int lk = lane >> 4;          // k-group 0..3

    f32x4 acc[8];
    #pragma unroll
    for (int ct = 0; ct < 8; ++ct) acc[ct] = (f32x4){0.f, 0.f, 0.f, 0.f};

    for (int chunk = 0; chunk < 5; ++chunk) {
        // stage A tile: rows m0..+63, k-cols chunk*32..+31 (8 floats/thread)
        {
            int r = t >> 2;
            int c = (t & 3) * 8;
            int m = m0 + r;
            float4 v0 = make_float4(0.f, 0.f, 0.f, 0.f), v1 = v0;
            if (m < N) {
                const float* src = (chunk < 4) ? &A0[(size_t)m * IN_SIZE + chunk * 32 + c]
                                               : &A1[(size_t)m * E_SIZE + c];
                v0 = *(const float4*)&src[0];
                v1 = *(const float4*)&src[4];
            }
            union { unsigned short u[8]; short8v v; } pk;
            pk.u[0] = f2bf(v0.x); pk.u[1] = f2bf(v0.y); pk.u[2] = f2bf(v0.z); pk.u[3] = f2bf(v0.w);
            pk.u[4] = f2bf(v1.x); pk.u[5] = f2bf(v1.y); pk.u[6] = f2bf(v1.z); pk.u[7] = f2bf(v1.w);
            *(short8v*)&As[r][c] = pk.v;
        }
        // stage B: Bs[n][kk] = W[n][chunk*32+kk] (16 floats/thread)
        {
            int n = t >> 1;
            int half = (t & 1) * 16;
            const float* wr = &W[(size_t)n * KDIM + chunk * 32 + half];
            float4 u0 = *(const float4*)&wr[0];
            float4 u1 = *(const float4*)&wr[4];
            float4 u2 = *(const float4*)&wr[8];
            float4 u3 = *(const float4*)&wr[12];
            union { unsigned short u[8]; short8v v; } p0, p1;
            p0.u[0] = f2bf(u0.x); p0.u[1] = f2bf(u0.y); p0.u[2] = f2bf(u0.z); p0.u[3] = f2bf(u0.w);
            p0.u[4] = f2bf(u1.x); p0.u[5] = f2bf(u1.y); p0.u[6] = f2bf(u1.z); p0.u[7] = f2bf(u1.w);
            p1.u[0] = f2bf(u2.x); p1.u[1] = f2bf(u2.y); p1.u[2] = f2bf(u2.z); p1.u[3] = f2bf(u2.w);
            p1.u[4] = f2bf(u3.x); p1.u[5] = f2bf(u3.y); p1.u[6] = f2bf(u3.z); p1.u[7] = f2bf(u3.w);
            *(short8v*)&Bs[n][half]     = p0.v;
            *(short8v*)&Bs[n][half + 8] = p1.v;
        }
        __syncthreads();

        short8v a = *(const short8v*)&As[w * 16 + lr][lk * 8];
        #pragma unroll
        for (int ct = 0; ct < 8; ++ct) {
            short8v bfr = *(const short8v*)&Bs[ct * 16 + lr][lk * 8];
            acc[ct] = __builtin_amdgcn_mfma_f32_16x16x32_bf16(a, bfr, acc[ct], 0, 0, 0);
        }
        __syncthreads();
    }

    #pragma unroll
    for (int ct = 0; ct < 8; ++ct) {
        #pragma unroll
        for (int j = 0; j < 4; ++j) {
            int m = m0 + w * 16 + lk * 4 + j;
            if (m < N) out[(size_t)m * IN_SIZE + ct * 16 + lr] = acc[ct][j];
        }
    }
}

// ---------------- launch ----------------

extern "C" void kernel_launch(void* const* d_in, const int* in_sizes, int n_in,
                              void* d_out, int out_size, void* d_ws, size_t ws_size,
                              hipStream_t stream) {
    const float* h_in = (const float*)d_in[0];
    const float* ef   = (const float*)d_in[1];
    const int*   dst  = (const int*)d_in[2];
    const float* W    = (const float*)d_in[3];
    float* out = (float*)d_out;
    int N = in_sizes[0] / IN_SIZE;     // 50000
    int E = in_sizes[2];               // 1600000
    int nbk = (N + BNODES - 1) >> BSHIFT;   // 782 buckets (<= NBK_MAX)

    // workspace carve-out (256B aligned)
    char* p = (char*)d_ws;
    auto take = [&](size_t bytes) { char* r = p; p += (bytes + 255) & ~(size_t)255; return r; };
    int*   slabA   = (int*)take((size_t)NSCAT * nbk * 4);
    int*   slabB   = (int*)take((size_t)NSCAT * nbk * 4);
    int*   bktcnt  = (int*)take((size_t)nbk * 4);
    int*   bktbase = (int*)take((size_t)(nbk + 1) * 4);
    int*   offsets = (int*)take((size_t)(N + 1) * 4);
    int*   binb    = (int*)take((size_t)E * 4);
    int*   eidsb   = (int*)take((size_t)E * 4);
    float* agg     = (float*)take((size_t)N * E_SIZE * 4);

    void* csr_args[] = { (void*)&dst, (void*)&slabA, (void*)&slabB, (void*)&bktcnt,
                         (void*)&bktbase, (void*)&binb, (void*)&eidsb, (void*)&offsets,
                         (void*)&E, (void*)&N, (void*)&nbk };
    hipLaunchCooperativeKernel((void*)k_csr, dim3(nbk), dim3(256), csr_args, 0, stream);
    k_node<<<(N + 3) / 4, 256, 0, stream>>>(ef, offsets, eidsb, agg, N);
    k_gemm<<<(N + 63) / 64, 256, 0, stream>>>(h_in, agg, W, out, N);
}

// Round 11
// 105.720 us; speedup vs baseline: 3.6437x; 3.6437x over previous
//
#include <hip/hip_runtime.h>
#include <math.h>

#define IN_SIZE 128
#define E_SIZE  32
#define KDIM    160
#define BSHIFT  6                    // 64 nodes per bucket
#define BNODES  (1 << BSHIFT)
#define NBK_MAX 1024                 // nbk = ceil(50000/64) = 782 <= 1024
#define NSCAT   256                  // blocks for hist/scatter (== threads in k_scan1)

typedef __attribute__((ext_vector_type(8))) short short8v;
typedef __attribute__((ext_vector_type(4))) float f32x4;

// ---------------- per-block bucket histogram -> slab (no global atomics) ----------------

__global__ __launch_bounds__(256) void k_bhist(
    const int* __restrict__ dst, int* __restrict__ slabA, int E, int nbk)
{
    __shared__ int hist[NBK_MAX];
    int tid = threadIdx.x;
    for (int k = tid; k < nbk; k += 256) hist[k] = 0;
    __syncthreads();
    int chunk = (E + NSCAT - 1) / NSCAT;
    int s = blockIdx.x * chunk;
    int e = s + chunk; if (e > E) e = E;
    for (int i = s + tid; i < e; i += 256)
        atomicAdd(&hist[dst[i] >> BSHIFT], 1);
    __syncthreads();
    for (int k = tid; k < nbk; k += 256)
        slabA[blockIdx.x * nbk + k] = hist[k];
}

// ---------------- scan stage 1: per-bucket prefix over the 256 block counts ----------------

__global__ __launch_bounds__(NSCAT) void k_scan1(
    const int* __restrict__ slabA, int* __restrict__ slabB,
    int* __restrict__ bktcnt, int nbk)
{
    __shared__ int s[NSCAT];
    int k = blockIdx.x, t = threadIdx.x;
    int v = slabA[t * nbk + k];
    s[t] = v;
    __syncthreads();
    for (int off = 1; off < NSCAT; off <<= 1) {     // Hillis-Steele inclusive
        int add = (t >= off) ? s[t - off] : 0;
        __syncthreads();
        s[t] += add;
        __syncthreads();
    }
    slabB[t * nbk + k] = s[t] - v;                  // exclusive within-bucket base for block t
    if (t == NSCAT - 1) bktcnt[k] = s[t];
}

// ---------------- fast in-LDS exclusive scan of bktcnt (1024 slots, 256 thr, 4/thread) ----

__device__ __forceinline__ void block_scan_bktcnt(
    const int* __restrict__ bktcnt, int nbk, int* base /*LDS[NBK_MAX]*/, int* wtot /*LDS[4]*/)
{
    int tid = threadIdx.x;
    int lane = tid & 63, wv = tid >> 6;
    int k0 = tid * 4;
    int v0 = (k0 + 0 < nbk) ? bktcnt[k0 + 0] : 0;
    int v1 = (k0 + 1 < nbk) ? bktcnt[k0 + 1] : 0;
    int v2 = (k0 + 2 < nbk) ? bktcnt[k0 + 2] : 0;
    int v3 = (k0 + 3 < nbk) ? bktcnt[k0 + 3] : 0;
    int tsum = v0 + v1 + v2 + v3;
    int x = tsum;
    #pragma unroll
    for (int off = 1; off < 64; off <<= 1) {
        int y = __shfl_up(x, off);
        if (lane >= off) x += y;
    }
    if (lane == 63) wtot[wv] = x;
    __syncthreads();
    if (tid == 0) {
        int r = 0;
        #pragma unroll
        for (int w = 0; w < 4; ++w) { int t = wtot[w]; wtot[w] = r; r += t; }
    }
    __syncthreads();
    int ex = wtot[wv] + (x - tsum);                 // exclusive base of element k0
    base[k0 + 0] = ex;
    base[k0 + 1] = ex + v0;
    base[k0 + 2] = ex + v0 + v1;
    base[k0 + 3] = ex + v0 + v1 + v2;
    __syncthreads();
}

// ---------------- scatter (single dst pass, LDS cursors; also publishes bktbase) --------
// bin entry packs (edge_id << 6) | (dst & 63); eid < 2^21 fits in 27 bits.

__global__ __launch_bounds__(256) void k_scatter(
    const int* __restrict__ dst, const int* __restrict__ slabB,
    const int* __restrict__ bktcnt, int* __restrict__ bktbase,
    int* __restrict__ bin, int E, int nbk)
{
    __shared__ int base[NBK_MAX];
    __shared__ int wtot[4];
    __shared__ int cur[NBK_MAX];
    int tid = threadIdx.x;
    block_scan_bktcnt(bktcnt, nbk, base, wtot);
    for (int k = tid; k < nbk; k += 256)
        cur[k] = base[k] + slabB[blockIdx.x * nbk + k];
    if (blockIdx.x == 0) {                          // publish bucket bases for k_fill3
        for (int k = tid; k < nbk; k += 256) bktbase[k] = base[k];
        if (tid == 0) bktbase[nbk] = E;
    }
    __syncthreads();
    int chunk = (E + NSCAT - 1) / NSCAT;
    int s = blockIdx.x * chunk;
    int e = s + chunk; if (e > E) e = E;
    for (int i = s + tid; i < e; i += 256) {
        int d = dst[i];
        int p = atomicAdd(&cur[d >> BSHIFT], 1);    // cursor holds GLOBAL position
        bin[p] = (i << BSHIFT) | (d & (BNODES - 1));
    }
}

// ---------------- per-bucket exact placement + offsets ----------------

__global__ __launch_bounds__(256) void k_fill3(
    const int* __restrict__ bktbase, const int* __restrict__ bin,
    int* __restrict__ eids, int* __restrict__ offsets, int N)
{
    __shared__ int cnt[BNODES];
    __shared__ int nb0[BNODES];
    int b = blockIdx.x;
    int n0 = b << BSHIFT;
    int tid = threadIdx.x;
    int s = bktbase[b];
    int e = bktbase[b + 1];
    if (tid < BNODES) cnt[tid] = 0;
    __syncthreads();
    for (int k = s + tid; k < e; k += 256)
        atomicAdd(&cnt[bin[k] & (BNODES - 1)], 1);
    __syncthreads();
    if (tid < BNODES) {                         // wave 0: shuffle scan of 64 degs
        int v = cnt[tid];
        int x = v;
        #pragma unroll
        for (int off = 1; off < 64; off <<= 1) {
            int y = __shfl_up(x, off);
            if (tid >= off) x += y;
        }
        int nodebase = s + x - v;               // exclusive
        nb0[tid] = nodebase;
        if (n0 + tid < N) offsets[n0 + tid] = nodebase;
        cnt[tid] = 0;                           // reuse as cursor
    }
    __syncthreads();
    for (int k = s + tid; k < e; k += 256) {
        int pk = bin[k];
        int ln = pk & (BNODES - 1);
        int p = nb0[ln] + atomicAdd(&cnt[ln], 1);
        eids[p] = pk >> BSHIFT;
    }
    if (b == 0 && tid == 0) offsets[N] = bktbase[(N + BNODES - 1) >> BSHIFT];
}

// ---------------- per-node aggregate (1 wave / node, 8 edges x 8 float4-lanes) ----------------
// Deg-adaptive: NIT=4 slots for deg<=32 (~55% of nodes), NIT=8 for deg<=64, dynamic beyond.

__device__ __forceinline__ float red_q(float x) {        // sum across q (lane bits 0..2)
    x += __shfl_xor(x, 1); x += __shfl_xor(x, 2); x += __shfl_xor(x, 4);
    return x;
}
__device__ __forceinline__ float red_es(float x) {       // sum across es (lane bits 3..5)
    x += __shfl_xor(x, 8); x += __shfl_xor(x, 16); x += __shfl_xor(x, 32);
    return x;
}
__device__ __forceinline__ float4 red_es4(float4 v) {
    v.x = red_es(v.x); v.y = red_es(v.y); v.z = red_es(v.z); v.w = red_es(v.w);
    return v;
}

template<int NIT>
__device__ __forceinline__ float4 node_aggregate(
    const float* __restrict__ ef, const int* __restrict__ eids,
    int start, int deg, int lane, int es, int q)
{
    int myeid = (lane < deg) ? eids[start + lane] : 0;

    float4 fc[NIT];
    #pragma unroll
    for (int it = 0; it < NIT; ++it) {
        int i = es + it * 8;
        int eid = __shfl(myeid, i);
        float4 f = make_float4(0.f, 0.f, 0.f, 0.f);
        if (i < deg)                        // uniform within each 8-lane q-group
            f = *(const float4*)&ef[(size_t)eid * E_SIZE + q * 4];
        fc[it] = f;
    }

    float4 esum = make_float4(0.f, 0.f, 0.f, 0.f);
    #pragma unroll
    for (int it = 0; it < NIT; ++it) {
        esum.x += fc[it].x; esum.y += fc[it].y; esum.z += fc[it].z; esum.w += fc[it].w;
    }
    for (int i = es + NIT * 8; i < deg; i += 8) {       // overflow: ~never
        int eid = eids[start + i];
        float4 f = *(const float4*)&ef[(size_t)eid * E_SIZE + q * 4];
        esum.x += f.x; esum.y += f.y; esum.z += f.z; esum.w += f.w;
    }
    esum = red_es4(esum);
    float inv = (deg > 0) ? 1.f / (float)deg : 0.f;
    float4 hk = make_float4(esum.x * inv, esum.y * inv, esum.z * inv, esum.w * inv);
    float hn2 = hk.x * hk.x + hk.y * hk.y + hk.z * hk.z + hk.w * hk.w;
    hn2 = red_q(hn2);
    float t2h = 0.25f * hn2;                            // THRESH^2 * ||hk||^2

    // cos < 0.5  <=>  num < 0 || num^2 < t2h*fn2  (sqrt/div-free; 0/0 -> excluded = jnp NaN)
    float4 ssum = make_float4(0.f, 0.f, 0.f, 0.f);
    float scnt = 0.f;
    #pragma unroll
    for (int it = 0; it < NIT; ++it) {
        float4 f = fc[it];
        float num = hk.x * f.x + hk.y * f.y + hk.z * f.z + hk.w * f.w;
        float fn2 = f.x * f.x + f.y * f.y + f.z * f.z + f.w * f.w;
        num = red_q(num);
        fn2 = red_q(fn2);
        if (num < 0.f || num * num < t2h * fn2) {
            ssum.x += f.x; ssum.y += f.y; ssum.z += f.z; ssum.w += f.w;
            scnt += (es + it * 8 < deg) ? 1.f : 0.f;    // count real edges only
        }
    }
    for (int i = es + NIT * 8; i < deg; i += 8) {       // overflow: ~never
        int eid = eids[start + i];
        float4 f = *(const float4*)&ef[(size_t)eid * E_SIZE + q * 4];
        float num = hk.x * f.x + hk.y * f.y + hk.z * f.z + hk.w * f.w;
        float fn2 = f.x * f.x + f.y * f.y + f.z * f.z + f.w * f.w;
        num = red_q(num);
        fn2 = red_q(fn2);
        if (num < 0.f || num * num < t2h * fn2) {
            ssum.x += f.x; ssum.y += f.y; ssum.z += f.z; ssum.w += f.w;
            scnt += 1.f;
        }
    }
    ssum = red_es4(ssum);
    scnt = red_es(scnt);

    float4 a;
    if (scnt > 0.f) {
        float r = 1.f / scnt;
        a = make_float4(ssum.x * r, ssum.y * r, ssum.z * r, ssum.w * r);
    } else {
        a = hk;
    }
    return a;
}

__global__ __launch_bounds__(256, 6) void k_node(
    const float* __restrict__ ef, const int* __restrict__ offsets,
    const int* __restrict__ eids, float* __restrict__ agg, int N)
{
    int wid = blockIdx.x * 4 + (threadIdx.x >> 6);   // node id
    if (wid >= N) return;
    int lane = threadIdx.x & 63;
    int es = lane >> 3;
    int q  = lane & 7;
    int start = offsets[wid];
    int deg   = offsets[wid + 1] - start;

    float4 a;
    if (deg <= 32) a = node_aggregate<4>(ef, eids, start, deg, lane, es, q);
    else           a = node_aggregate<8>(ef, eids, start, deg, lane, es, q);

    if (es == 0) *(float4*)&agg[(size_t)wid * E_SIZE + q * 4] = a;
}

// ---------------- GEMM (bf16 MFMA): out[N][128] = [h_in | agg] @ W^T ----------------
// BM=64, BN=128 (full), K=160=5x32; 782 blocks, 256 thr = 4 waves; wave w owns rows w*16..+15.
// mfma_f32_16x16x32_bf16 maps: a: row=lane&15, k=(lane>>4)*8+i; b: col=lane&15;
// d: row=(lane>>4)*4+j, col=lane&15. f32 accumulate; bf16 rounding ~0.03 << 0.116 threshold
// (verified R10: absmax 0.03125, passed).

__device__ __forceinline__ unsigned short f2bf(float x) {   // RNE fp32->bf16
    union { float f; unsigned int u; } c; c.f = x;
    unsigned int r = c.u + 0x7FFFu + ((c.u >> 16) & 1u);
    return (unsigned short)(r >> 16);
}

__global__ __launch_bounds__(256) void k_gemm(
    const float* __restrict__ A0,   // h_in [N][128]
    const float* __restrict__ A1,   // agg  [N][32]
    const float* __restrict__ W,    // [128][160]
    float* __restrict__ out, int N)
{
    __shared__ unsigned short As[64][40];    // bf16, pad-40: 16B-aligned rows, <=2-way banks
    __shared__ unsigned short Bs[128][40];   // Bs[n][kk] = W[n][k0+kk] (bf16)
    int t = threadIdx.x;
    int m0 = blockIdx.x * 64;
    int w = t >> 6, lane = t & 63;
    int lr = lane & 15;          // row (A) / col (B,D) within 16
    int lk = lane >> 4;          // k-group 0..3

    f32x4 acc[8];
    #pragma unroll
    for (int ct = 0; ct < 8; ++ct) acc[ct] = (f32x4){0.f, 0.f, 0.f, 0.f};

    for (int chunk = 0; chunk < 5; ++chunk) {
        // stage A tile: rows m0..+63, k-cols chunk*32..+31 (8 floats/thread)
        {
            int r = t >> 2;
            int c = (t & 3) * 8;
            int m = m0 + r;
            float4 v0 = make_float4(0.f, 0.f, 0.f, 0.f), v1 = v0;
            if (m < N) {
                const float* src = (chunk < 4) ? &A0[(size_t)m * IN_SIZE + chunk * 32 + c]
                                               : &A1[(size_t)m * E_SIZE + c];
                v0 = *(const float4*)&src[0];
                v1 = *(const float4*)&src[4];
            }
            union { unsigned short u[8]; short8v v; } pk;
            pk.u[0] = f2bf(v0.x); pk.u[1] = f2bf(v0.y); pk.u[2] = f2bf(v0.z); pk.u[3] = f2bf(v0.w);
            pk.u[4] = f2bf(v1.x); pk.u[5] = f2bf(v1.y); pk.u[6] = f2bf(v1.z); pk.u[7] = f2bf(v1.w);
            *(short8v*)&As[r][c] = pk.v;
        }
        // stage B: Bs[n][kk] = W[n][chunk*32+kk] (16 floats/thread)
        {
            int n = t >> 1;
            int half = (t & 1) * 16;
            const float* wr = &W[(size_t)n * KDIM + chunk * 32 + half];
            float4 u0 = *(const float4*)&wr[0];
            float4 u1 = *(const float4*)&wr[4];
            float4 u2 = *(const float4*)&wr[8];
            float4 u3 = *(const float4*)&wr[12];
            union { unsigned short u[8]; short8v v; } p0, p1;
            p0.u[0] = f2bf(u0.x); p0.u[1] = f2bf(u0.y); p0.u[2] = f2bf(u0.z); p0.u[3] = f2bf(u0.w);
            p0.u[4] = f2bf(u1.x); p0.u[5] = f2bf(u1.y); p0.u[6] = f2bf(u1.z); p0.u[7] = f2bf(u1.w);
            p1.u[0] = f2bf(u2.x); p1.u[1] = f2bf(u2.y); p1.u[2] = f2bf(u2.z); p1.u[3] = f2bf(u2.w);
            p1.u[4] = f2bf(u3.x); p1.u[5] = f2bf(u3.y); p1.u[6] = f2bf(u3.z); p1.u[7] = f2bf(u3.w);
            *(short8v*)&Bs[n][half]     = p0.v;
            *(short8v*)&Bs[n][half + 8] = p1.v;
        }
        __syncthreads();

        short8v a = *(const short8v*)&As[w * 16 + lr][lk * 8];
        #pragma unroll
        for (int ct = 0; ct < 8; ++ct) {
            short8v bfr = *(const short8v*)&Bs[ct * 16 + lr][lk * 8];
            acc[ct] = __builtin_amdgcn_mfma_f32_16x16x32_bf16(a, bfr, acc[ct], 0, 0, 0);
        }
        __syncthreads();
    }

    #pragma unroll
    for (int ct = 0; ct < 8; ++ct) {
        #pragma unroll
        for (int j = 0; j < 4; ++j) {
            int m = m0 + w * 16 + lk * 4 + j;
            if (m < N) out[(size_t)m * IN_SIZE + ct * 16 + lr] = acc[ct][j];
        }
    }
}

// ---------------- launch ----------------

extern "C" void kernel_launch(void* const* d_in, const int* in_sizes, int n_in,
                              void* d_out, int out_size, void* d_ws, size_t ws_size,
                              hipStream_t stream) {
    const float* h_in = (const float*)d_in[0];
    const float* ef   = (const float*)d_in[1];
    const int*   dst  = (const int*)d_in[2];
    const float* W    = (const float*)d_in[3];
    float* out = (float*)d_out;
    int N = in_sizes[0] / IN_SIZE;     // 50000
    int E = in_sizes[2];               // 1600000
    int nbk = (N + BNODES - 1) >> BSHIFT;   // 782 buckets (<= NBK_MAX)

    // workspace carve-out (256B aligned)
    char* p = (char*)d_ws;
    auto take = [&](size_t bytes) { char* r = p; p += (bytes + 255) & ~(size_t)255; return r; };
    int*   slabA   = (int*)take((size_t)NSCAT * nbk * 4);
    int*   slabB   = (int*)take((size_t)NSCAT * nbk * 4);
    int*   bktcnt  = (int*)take((size_t)nbk * 4);
    int*   bktbase = (int*)take((size_t)(nbk + 1) * 4);
    int*   offsets = (int*)take((size_t)(N + 1) * 4);
    int*   binb    = (int*)take((size_t)E * 4);
    int*   eidsb   = (int*)take((size_t)E * 4);
    float* agg     = (float*)take((size_t)N * E_SIZE * 4);

    k_bhist  <<<NSCAT, 256, 0, stream>>>(dst, slabA, E, nbk);
    k_scan1  <<<nbk, NSCAT, 0, stream>>>(slabA, slabB, bktcnt, nbk);
    k_scatter<<<NSCAT, 256, 0, stream>>>(dst, slabB, bktcnt, bktbase, binb, E, nbk);
    k_fill3  <<<nbk, 256, 0, stream>>>(bktbase, binb, eidsb, offsets, N);
    k_node   <<<(N + 3) / 4, 256, 0, stream>>>(ef, offsets, eidsb, agg, N);
    k_gemm   <<<(N + 63) / 64, 256, 0, stream>>>(h_in, agg, W, out, N);
}

// Round 12
// 98.157 us; speedup vs baseline: 3.9245x; 1.0770x over previous
//
#include <hip/hip_runtime.h>
#include <math.h>

#define IN_SIZE 128
#define E_SIZE  32
#define KDIM    160
#define BSHIFT  6                    // 64 nodes per bucket
#define BNODES  (1 << BSHIFT)
#define NBK_MAX 1024                 // nbk = ceil(50000/64) = 782 <= 1024
#define NSCAT   256                  // blocks for hist/scatter (== threads in k_scan1)

typedef __attribute__((ext_vector_type(8))) short short8v;
typedef __attribute__((ext_vector_type(4))) float f32x4;

// chunk per hist/scatter block, aligned to 16 edges so int4 loads are 16B-aligned
__host__ __device__ __forceinline__ int chunk16(int E) {
    return (((E + NSCAT - 1) / NSCAT) + 15) & ~15;
}

// ---------------- per-block bucket histogram -> slab (no global atomics; int4 loads) ------

__global__ __launch_bounds__(256) void k_bhist(
    const int* __restrict__ dst, int* __restrict__ slabA, int E, int nbk)
{
    __shared__ int hist[NBK_MAX];
    int tid = threadIdx.x;
    for (int k = tid; k < nbk; k += 256) hist[k] = 0;
    __syncthreads();
    int chunk = chunk16(E);
    int s = blockIdx.x * chunk;
    int e = s + chunk; if (e > E) e = E;          // E%4==0 and s%16==0 -> int4 loop exact
    for (int i = s + tid * 4; i < e; i += 256 * 4) {
        int4 d4 = *(const int4*)&dst[i];
        atomicAdd(&hist[d4.x >> BSHIFT], 1);
        atomicAdd(&hist[d4.y >> BSHIFT], 1);
        atomicAdd(&hist[d4.z >> BSHIFT], 1);
        atomicAdd(&hist[d4.w >> BSHIFT], 1);
    }
    __syncthreads();
    for (int k = tid; k < nbk; k += 256)
        slabA[blockIdx.x * nbk + k] = hist[k];
}

// ---------------- scan stage 1: per-bucket prefix over the 256 block counts ----------------

__global__ __launch_bounds__(NSCAT) void k_scan1(
    const int* __restrict__ slabA, int* __restrict__ slabB,
    int* __restrict__ bktcnt, int nbk)
{
    __shared__ int s[NSCAT];
    int k = blockIdx.x, t = threadIdx.x;
    int v = slabA[t * nbk + k];
    s[t] = v;
    __syncthreads();
    for (int off = 1; off < NSCAT; off <<= 1) {     // Hillis-Steele inclusive
        int add = (t >= off) ? s[t - off] : 0;
        __syncthreads();
        s[t] += add;
        __syncthreads();
    }
    slabB[t * nbk + k] = s[t] - v;                  // exclusive within-bucket base for block t
    if (t == NSCAT - 1) bktcnt[k] = s[t];
}

// ---------------- fast in-LDS exclusive scan of bktcnt (1024 slots, 256 thr, 4/thread) ----

__device__ __forceinline__ void block_scan_bktcnt(
    const int* __restrict__ bktcnt, int nbk, int* base /*LDS[NBK_MAX]*/, int* wtot /*LDS[4]*/)
{
    int tid = threadIdx.x;
    int lane = tid & 63, wv = tid >> 6;
    int k0 = tid * 4;
    int v0 = (k0 + 0 < nbk) ? bktcnt[k0 + 0] : 0;
    int v1 = (k0 + 1 < nbk) ? bktcnt[k0 + 1] : 0;
    int v2 = (k0 + 2 < nbk) ? bktcnt[k0 + 2] : 0;
    int v3 = (k0 + 3 < nbk) ? bktcnt[k0 + 3] : 0;
    int tsum = v0 + v1 + v2 + v3;
    int x = tsum;
    #pragma unroll
    for (int off = 1; off < 64; off <<= 1) {
        int y = __shfl_up(x, off);
        if (lane >= off) x += y;
    }
    if (lane == 63) wtot[wv] = x;
    __syncthreads();
    if (tid == 0) {
        int r = 0;
        #pragma unroll
        for (int w = 0; w < 4; ++w) { int t = wtot[w]; wtot[w] = r; r += t; }
    }
    __syncthreads();
    int ex = wtot[wv] + (x - tsum);                 // exclusive base of element k0
    base[k0 + 0] = ex;
    base[k0 + 1] = ex + v0;
    base[k0 + 2] = ex + v0 + v1;
    base[k0 + 3] = ex + v0 + v1 + v2;
    __syncthreads();
}

// ---------------- scatter (single int4 dst pass, LDS cursors; publishes bktbase) --------
// bin entry packs (edge_id << 6) | (dst & 63); eid < 2^21 fits in 27 bits.

__global__ __launch_bounds__(256) void k_scatter(
    const int* __restrict__ dst, const int* __restrict__ slabB,
    const int* __restrict__ bktcnt, int* __restrict__ bktbase,
    int* __restrict__ bin, int E, int nbk)
{
    __shared__ int base[NBK_MAX];
    __shared__ int wtot[4];
    __shared__ int cur[NBK_MAX];
    int tid = threadIdx.x;
    block_scan_bktcnt(bktcnt, nbk, base, wtot);
    for (int k = tid; k < nbk; k += 256)
        cur[k] = base[k] + slabB[blockIdx.x * nbk + k];
    if (blockIdx.x == 0) {                          // publish bucket bases for k_fill3
        for (int k = tid; k < nbk; k += 256) bktbase[k] = base[k];
        if (tid == 0) bktbase[nbk] = E;
    }
    __syncthreads();
    int chunk = chunk16(E);
    int s = blockIdx.x * chunk;
    int e = s + chunk; if (e > E) e = E;
    for (int i = s + tid * 4; i < e; i += 256 * 4) {
        int4 d4 = *(const int4*)&dst[i];
        int p0 = atomicAdd(&cur[d4.x >> BSHIFT], 1);
        bin[p0] = ((i + 0) << BSHIFT) | (d4.x & (BNODES - 1));
        int p1 = atomicAdd(&cur[d4.y >> BSHIFT], 1);
        bin[p1] = ((i + 1) << BSHIFT) | (d4.y & (BNODES - 1));
        int p2 = atomicAdd(&cur[d4.z >> BSHIFT], 1);
        bin[p2] = ((i + 2) << BSHIFT) | (d4.z & (BNODES - 1));
        int p3 = atomicAdd(&cur[d4.w >> BSHIFT], 1);
        bin[p3] = ((i + 3) << BSHIFT) | (d4.w & (BNODES - 1));
    }
}

// ---------------- per-bucket exact placement + offsets ----------------

__global__ __launch_bounds__(256) void k_fill3(
    const int* __restrict__ bktbase, const int* __restrict__ bin,
    int* __restrict__ eids, int* __restrict__ offsets, int N)
{
    __shared__ int cnt[BNODES];
    __shared__ int nb0[BNODES];
    int b = blockIdx.x;
    int n0 = b << BSHIFT;
    int tid = threadIdx.x;
    int s = bktbase[b];
    int e = bktbase[b + 1];
    if (tid < BNODES) cnt[tid] = 0;
    __syncthreads();
    #pragma unroll 4
    for (int k = s + tid; k < e; k += 256)
        atomicAdd(&cnt[bin[k] & (BNODES - 1)], 1);
    __syncthreads();
    if (tid < BNODES) {                         // wave 0: shuffle scan of 64 degs
        int v = cnt[tid];
        int x = v;
        #pragma unroll
        for (int off = 1; off < 64; off <<= 1) {
            int y = __shfl_up(x, off);
            if (tid >= off) x += y;
        }
        int nodebase = s + x - v;               // exclusive
        nb0[tid] = nodebase;
        if (n0 + tid < N) offsets[n0 + tid] = nodebase;
        cnt[tid] = 0;                           // reuse as cursor
    }
    __syncthreads();
    #pragma unroll 4
    for (int k = s + tid; k < e; k += 256) {
        int pk = bin[k];
        int ln = pk & (BNODES - 1);
        int p = nb0[ln] + atomicAdd(&cnt[ln], 1);
        eids[p] = pk >> BSHIFT;
    }
    if (b == 0 && tid == 0) offsets[N] = bktbase[(N + BNODES - 1) >> BSHIFT];
}

// ---------------- per-node aggregate (1 wave / node, 8 edges x 8 float4-lanes) ----------------
// Deg-adaptive: NIT=4 slots for deg<=32 (~55% of nodes), NIT=8 for deg<=64, dynamic beyond.

__device__ __forceinline__ float red_q(float x) {        // sum across q (lane bits 0..2)
    x += __shfl_xor(x, 1); x += __shfl_xor(x, 2); x += __shfl_xor(x, 4);
    return x;
}
__device__ __forceinline__ float red_es(float x) {       // sum across es (lane bits 3..5)
    x += __shfl_xor(x, 8); x += __shfl_xor(x, 16); x += __shfl_xor(x, 32);
    return x;
}
__device__ __forceinline__ float4 red_es4(float4 v) {
    v.x = red_es(v.x); v.y = red_es(v.y); v.z = red_es(v.z); v.w = red_es(v.w);
    return v;
}

template<int NIT>
__device__ __forceinline__ float4 node_aggregate(
    const float* __restrict__ ef, const int* __restrict__ eids,
    int start, int deg, int lane, int es, int q)
{
    int myeid = (lane < deg) ? eids[start + lane] : 0;

    float4 fc[NIT];
    #pragma unroll
    for (int it = 0; it < NIT; ++it) {
        int i = es + it * 8;
        int eid = __shfl(myeid, i);
        float4 f = make_float4(0.f, 0.f, 0.f, 0.f);
        if (i < deg)                        // uniform within each 8-lane q-group
            f = *(const float4*)&ef[(size_t)eid * E_SIZE + q * 4];
        fc[it] = f;
    }

    float4 esum = make_float4(0.f, 0.f, 0.f, 0.f);
    #pragma unroll
    for (int it = 0; it < NIT; ++it) {
        esum.x += fc[it].x; esum.y += fc[it].y; esum.z += fc[it].z; esum.w += fc[it].w;
    }
    for (int i = es + NIT * 8; i < deg; i += 8) {       // overflow: ~never
        int eid = eids[start + i];
        float4 f = *(const float4*)&ef[(size_t)eid * E_SIZE + q * 4];
        esum.x += f.x; esum.y += f.y; esum.z += f.z; esum.w += f.w;
    }
    esum = red_es4(esum);
    float inv = (deg > 0) ? 1.f / (float)deg : 0.f;
    float4 hk = make_float4(esum.x * inv, esum.y * inv, esum.z * inv, esum.w * inv);
    float hn2 = hk.x * hk.x + hk.y * hk.y + hk.z * hk.z + hk.w * hk.w;
    hn2 = red_q(hn2);
    float t2h = 0.25f * hn2;                            // THRESH^2 * ||hk||^2

    // cos < 0.5  <=>  num < 0 || num^2 < t2h*fn2  (sqrt/div-free; 0/0 -> excluded = jnp NaN)
    float4 ssum = make_float4(0.f, 0.f, 0.f, 0.f);
    float scnt = 0.f;
    #pragma unroll
    for (int it = 0; it < NIT; ++it) {
        float4 f = fc[it];
        float num = hk.x * f.x + hk.y * f.y + hk.z * f.z + hk.w * f.w;
        float fn2 = f.x * f.x + f.y * f.y + f.z * f.z + f.w * f.w;
        num = red_q(num);
        fn2 = red_q(fn2);
        if (num < 0.f || num * num < t2h * fn2) {
            ssum.x += f.x; ssum.y += f.y; ssum.z += f.z; ssum.w += f.w;
            scnt += (es + it * 8 < deg) ? 1.f : 0.f;    // count real edges only
        }
    }
    for (int i = es + NIT * 8; i < deg; i += 8) {       // overflow: ~never
        int eid = eids[start + i];
        float4 f = *(const float4*)&ef[(size_t)eid * E_SIZE + q * 4];
        float num = hk.x * f.x + hk.y * f.y + hk.z * f.z + hk.w * f.w;
        float fn2 = f.x * f.x + f.y * f.y + f.z * f.z + f.w * f.w;
        num = red_q(num);
        fn2 = red_q(fn2);
        if (num < 0.f || num * num < t2h * fn2) {
            ssum.x += f.x; ssum.y += f.y; ssum.z += f.z; ssum.w += f.w;
            scnt += 1.f;
        }
    }
    ssum = red_es4(ssum);
    scnt = red_es(scnt);

    float4 a;
    if (scnt > 0.f) {
        float r = 1.f / scnt;
        a = make_float4(ssum.x * r, ssum.y * r, ssum.z * r, ssum.w * r);
    } else {
        a = hk;
    }
    return a;
}

__global__ __launch_bounds__(256, 6) void k_node(
    const float* __restrict__ ef, const int* __restrict__ offsets,
    const int* __restrict__ eids, float* __restrict__ agg, int N)
{
    int wid = blockIdx.x * 4 + (threadIdx.x >> 6);   // node id
    if (wid >= N) return;
    int lane = threadIdx.x & 63;
    int es = lane >> 3;
    int q  = lane & 7;
    int start = offsets[wid];
    int deg   = offsets[wid + 1] - start;

    float4 a;
    if (deg <= 32) a = node_aggregate<4>(ef, eids, start, deg, lane, es, q);
    else           a = node_aggregate<8>(ef, eids, start, deg, lane, es, q);

    if (es == 0) *(float4*)&agg[(size_t)wid * E_SIZE + q * 4] = a;
}

// ---------------- GEMM (bf16 MFMA): out[N][128] = [h_in | agg] @ W^T ----------------
// BM=64, BN=128 (full), K=160=5x32; 782 blocks, 256 thr = 4 waves; wave w owns rows w*16..+15.
// mfma_f32_16x16x32_bf16 maps: a: row=lane&15, k=(lane>>4)*8+i; b: col=lane&15;
// d: row=(lane>>4)*4+j, col=lane&15. f32 accumulate; bf16 rounding absmax 0.03125 (verified).

__device__ __forceinline__ unsigned short f2bf(float x) {   // RNE fp32->bf16
    union { float f; unsigned int u; } c; c.f = x;
    unsigned int r = c.u + 0x7FFFu + ((c.u >> 16) & 1u);
    return (unsigned short)(r >> 16);
}

__global__ __launch_bounds__(256) void k_gemm(
    const float* __restrict__ A0,   // h_in [N][128]
    const float* __restrict__ A1,   // agg  [N][32]
    const float* __restrict__ W,    // [128][160]
    float* __restrict__ out, int N)
{
    __shared__ unsigned short As[64][40];    // bf16, pad-40: 16B-aligned rows, <=2-way banks
    __shared__ unsigned short Bs[128][40];   // Bs[n][kk] = W[n][k0+kk] (bf16)
    int t = threadIdx.x;
    int m0 = blockIdx.x * 64;
    int w = t >> 6, lane = t & 63;
    int lr = lane & 15;          // row (A) / col (B,D) within 16
    int lk = lane >> 4;          // k-group 0..3

    f32x4 acc[8];
    #pragma unroll
    for (int ct = 0; ct < 8; ++ct) acc[ct] = (f32x4){0.f, 0.f, 0.f, 0.f};

    for (int chunk = 0; chunk < 5; ++chunk) {
        // stage A tile: rows m0..+63, k-cols chunk*32..+31 (8 floats/thread)
        {
            int r = t >> 2;
            int c = (t & 3) * 8;
            int m = m0 + r;
            float4 v0 = make_float4(0.f, 0.f, 0.f, 0.f), v1 = v0;
            if (m < N) {
                const float* src = (chunk < 4) ? &A0[(size_t)m * IN_SIZE + chunk * 32 + c]
                                               : &A1[(size_t)m * E_SIZE + c];
                v0 = *(const float4*)&src[0];
                v1 = *(const float4*)&src[4];
            }
            union { unsigned short u[8]; short8v v; } pk;
            pk.u[0] = f2bf(v0.x); pk.u[1] = f2bf(v0.y); pk.u[2] = f2bf(v0.z); pk.u[3] = f2bf(v0.w);
            pk.u[4] = f2bf(v1.x); pk.u[5] = f2bf(v1.y); pk.u[6] = f2bf(v1.z); pk.u[7] = f2bf(v1.w);
            *(short8v*)&As[r][c] = pk.v;
        }
        // stage B: Bs[n][kk] = W[n][chunk*32+kk] (16 floats/thread)
        {
            int n = t >> 1;
            int half = (t & 1) * 16;
            const float* wr = &W[(size_t)n * KDIM + chunk * 32 + half];
            float4 u0 = *(const float4*)&wr[0];
            float4 u1 = *(const float4*)&wr[4];
            float4 u2 = *(const float4*)&wr[8];
            float4 u3 = *(const float4*)&wr[12];
            union { unsigned short u[8]; short8v v; } p0, p1;
            p0.u[0] = f2bf(u0.x); p0.u[1] = f2bf(u0.y); p0.u[2] = f2bf(u0.z); p0.u[3] = f2bf(u0.w);
            p0.u[4] = f2bf(u1.x); p0.u[5] = f2bf(u1.y); p0.u[6] = f2bf(u1.z); p0.u[7] = f2bf(u1.w);
            p1.u[0] = f2bf(u2.x); p1.u[1] = f2bf(u2.y); p1.u[2] = f2bf(u2.z); p1.u[3] = f2bf(u2.w);
            p1.u[4] = f2bf(u3.x); p1.u[5] = f2bf(u3.y); p1.u[6] = f2bf(u3.z); p1.u[7] = f2bf(u3.w);
            *(short8v*)&Bs[n][half]     = p0.v;
            *(short8v*)&Bs[n][half + 8] = p1.v;
        }
        __syncthreads();

        short8v a = *(const short8v*)&As[w * 16 + lr][lk * 8];
        #pragma unroll
        for (int ct = 0; ct < 8; ++ct) {
            short8v bfr = *(const short8v*)&Bs[ct * 16 + lr][lk * 8];
            acc[ct] = __builtin_amdgcn_mfma_f32_16x16x32_bf16(a, bfr, acc[ct], 0, 0, 0);
        }
        __syncthreads();
    }

    #pragma unroll
    for (int ct = 0; ct < 8; ++ct) {
        #pragma unroll
        for (int j = 0; j < 4; ++j) {
            int m = m0 + w * 16 + lk * 4 + j;
            if (m < N) out[(size_t)m * IN_SIZE + ct * 16 + lr] = acc[ct][j];
        }
    }
}

// ---------------- launch ----------------

extern "C" void kernel_launch(void* const* d_in, const int* in_sizes, int n_in,
                              void* d_out, int out_size, void* d_ws, size_t ws_size,
                              hipStream_t stream) {
    const float* h_in = (const float*)d_in[0];
    const float* ef   = (const float*)d_in[1];
    const int*   dst  = (const int*)d_in[2];
    const float* W    = (const float*)d_in[3];
    float* out = (float*)d_out;
    int N = in_sizes[0] / IN_SIZE;     // 50000
    int E = in_sizes[2];               // 1600000
    int nbk = (N + BNODES - 1) >> BSHIFT;   // 782 buckets (<= NBK_MAX)

    // workspace carve-out (256B aligned)
    char* p = (char*)d_ws;
    auto take = [&](size_t bytes) { char* r = p; p += (bytes + 255) & ~(size_t)255; return r; };
    int*   slabA   = (int*)take((size_t)NSCAT * nbk * 4);
    int*   slabB   = (int*)take((size_t)NSCAT * nbk * 4);
    int*   bktcnt  = (int*)take((size_t)nbk * 4);
    int*   bktbase = (int*)take((size_t)(nbk + 1) * 4);
    int*   offsets = (int*)take((size_t)(N + 1) * 4);
    int*   binb    = (int*)take((size_t)E * 4);
    int*   eidsb   = (int*)take((size_t)E * 4);
    float* agg     = (float*)take((size_t)N * E_SIZE * 4);

    k_bhist  <<<NSCAT, 256, 0, stream>>>(dst, slabA, E, nbk);
    k_scan1  <<<nbk, NSCAT, 0, stream>>>(slabA, slabB, bktcnt, nbk);
    k_scatter<<<NSCAT, 256, 0, stream>>>(dst, slabB, bktcnt, bktbase, binb, E, nbk);
    k_fill3  <<<nbk, 256, 0, stream>>>(bktbase, binb, eidsb, offsets, N);
    k_node   <<<(N + 3) / 4, 256, 0, stream>>>(ef, offsets, eidsb, agg, N);
    k_gemm   <<<(N + 63) / 64, 256, 0, stream>>>(h_in, agg, W, out, N);
}